// Round 3
// baseline (50536.969 us; speedup 1.0000x reference)
//
#include <hip/hip_runtime.h>
#include <cmath>

#define BATCH 4
#define TSEQ  128
#define HH    100
#define WW    464
#define CC    128
#define EMBD  300
#define HIDD  600
#define GATE4 2400
#define NPIX  (HH*WW)                 // 46400
#define IMG   ((size_t)BATCH*NPIX*CC) // 23,756,800 floats

// ---- workspace layout (in floats) ----
#define OFF_A  ((size_t)0)
#define OFF_B  (IMG)
#define OFF_C  (2*IMG)
#define OFF_XG (3*IMG)
#define SZ_XG  ((size_t)2*BATCH*TSEQ*GATE4)   // 2,457,600
#define OFF_H  (OFF_XG + SZ_XG)
#define SZ_H   ((size_t)2*2*BATCH*HIDD)        // 9600 (parity,dir,b,u)
#define OFF_CS (OFF_H + SZ_H)
#define SZ_CS  ((size_t)2*BATCH*HIDD)          // 4800
#define OFF_TS (OFF_CS + SZ_CS)
#define SZ_TS  ((size_t)2*BATCH*HIDD)          // 4800
#define OFF_K  (OFF_TS + SZ_TS)
#define SZ_K   ((size_t)2*BATCH*CC*CC)         // 131072
#define OFF_W  (OFF_K + SZ_K)
#define WSLOT  (25*CC*CC)                      // 409,600 halfs per slot
#define WELEMS (5*WSLOT)                       // 2,048,000 halfs per plane

typedef _Float16 f16x8 __attribute__((ext_vector_type(8)));
typedef _Float16 f16x4 __attribute__((ext_vector_type(4)));
typedef float    f32x4 __attribute__((ext_vector_type(4)));

__global__ void zero_f(float* p, int n) {
    int i = blockIdx.x*blockDim.x + threadIdx.x;
    if (i < n) p[i] = 0.f;
}

// ---- weight pre-convert: fp32 (tap,ic,oc) -> f16 hi/lo planes (slot,tap,oc,ic) ----
// slots: 0=conv1 1=conv2 2=deconv2 3=deconv1[ic 0..127 = h2] 4=deconv1[ic 128..255 = g1]
__global__ void wcvt(const float* __restrict__ c1, const float* __restrict__ c2,
                     const float* __restrict__ dc2, const float* __restrict__ dc1,
                     _Float16* __restrict__ whi, _Float16* __restrict__ wlo)
{
    int e = blockIdx.x*256 + threadIdx.x;      // < WELEMS
    int slot = e / WSLOT;
    int r = e % WSLOT;
    int tap = r >> 14;
    int r2 = r & 16383;
    int oc = r2 >> 7, ic = r2 & 127;
    const float* s; size_t si;
    if      (slot == 0) { s = c1;  si = ((size_t)tap*128 + ic)*128 + oc; }
    else if (slot == 1) { s = c2;  si = ((size_t)tap*128 + ic)*128 + oc; }
    else if (slot == 2) { s = dc2; si = ((size_t)tap*128 + ic)*128 + oc; }
    else if (slot == 3) { s = dc1; si = ((size_t)tap*256 + ic)*128 + oc; }
    else                { s = dc1; si = ((size_t)tap*256 + 128 + ic)*128 + oc; }
    float v = s[si];
    _Float16 h  = (_Float16)v;
    _Float16 lo = (_Float16)(v - (float)h);
    whi[e] = h; wlo[e] = lo;
}

// text = embed[instr]; xg[dir] = (dir? rev(text):text) @ Wx + b
// tiled: 16 timesteps per block, weights read once per (j, t-tile).
// grid (10, 2dir*4b*8ttile = 64), block 256
__global__ void embed_xg(const int* __restrict__ instr, const int* __restrict__ lens,
                         const float* __restrict__ etab,
                         const float* __restrict__ fWx, const float* __restrict__ fb,
                         const float* __restrict__ bWx, const float* __restrict__ bb,
                         float* __restrict__ xg)
{
    int gy  = blockIdx.y;
    int dir = gy >> 5;
    int b   = (gy >> 3) & 3;
    int tt  = gy & 7;
    int t0  = tt*16;
    int j   = blockIdx.x*256 + threadIdx.x;
    __shared__ int tok[16];
    __shared__ __attribute__((aligned(16))) float rows_t[EMBD][16];  // 19.2 KB
    int L = lens[b];
    if (threadIdx.x < 16) {
        int t = t0 + threadIdx.x;
        int tsel = (dir == 1 && t < L) ? (L - 1 - t) : t;
        tok[threadIdx.x] = instr[b*TSEQ + tsel];
    }
    __syncthreads();
    for (int idx = threadIdx.x; idx < 16*EMBD; idx += 256) {
        int k = idx >> 4, r = idx & 15;
        rows_t[k][r] = etab[(size_t)tok[r]*EMBD + k];
    }
    __syncthreads();
    if (j >= GATE4) return;
    const float* Wx   = dir ? bWx : fWx;
    const float* bias = dir ? bb  : fb;
    float bv = bias[j];
    float acc[16];
    #pragma unroll
    for (int r = 0; r < 16; ++r) acc[r] = bv;
    for (int k = 0; k < EMBD; ++k) {
        float w = Wx[(size_t)k*GATE4 + j];
        float4 a0 = *reinterpret_cast<const float4*>(&rows_t[k][0]);
        float4 a1 = *reinterpret_cast<const float4*>(&rows_t[k][4]);
        float4 a2 = *reinterpret_cast<const float4*>(&rows_t[k][8]);
        float4 a3 = *reinterpret_cast<const float4*>(&rows_t[k][12]);
        acc[0]+=a0.x*w;  acc[1]+=a0.y*w;  acc[2]+=a0.z*w;  acc[3]+=a0.w*w;
        acc[4]+=a1.x*w;  acc[5]+=a1.y*w;  acc[6]+=a1.z*w;  acc[7]+=a1.w*w;
        acc[8]+=a2.x*w;  acc[9]+=a2.y*w;  acc[10]+=a2.z*w; acc[11]+=a2.w*w;
        acc[12]+=a3.x*w; acc[13]+=a3.y*w; acc[14]+=a3.z*w; acc[15]+=a3.w*w;
    }
    float* o = xg + ((size_t)(dir*BATCH + b)*TSEQ + t0)*GATE4 + j;
    #pragma unroll
    for (int r = 0; r < 16; ++r) o[(size_t)r*GATE4] = acc[r];
}

// one recurrence step, both dirs. grid 24 = 2dir*4b*3ublk, block 256
__global__ void lstm_step(const float* __restrict__ xg,
                          const float* __restrict__ fWh, const float* __restrict__ bWh,
                          const int* __restrict__ lens,
                          float* __restrict__ hbuf, float* __restrict__ cbuf,
                          float* __restrict__ tsum, int t)
{
    int blk = blockIdx.x;
    int dir = blk / 12;
    int rem = blk % 12;
    int b = rem / 3, ublk = rem % 3;
    int u = ublk*256 + threadIdx.x;
    __shared__ float hl[HIDD];
    const float* hprev = hbuf + (((size_t)(t&1)*2 + dir)*BATCH + b)*HIDD;
    for (int k = threadIdx.x; k < HIDD; k += 256) hl[k] = hprev[k];
    __syncthreads();
    if (u >= HIDD) return;
    const float* Wh = dir ? bWh : fWh;
    const float* x  = xg + ((size_t)(dir*BATCH + b)*TSEQ + t)*GATE4;
    float ai = x[u], af = x[HIDD+u], ac = x[2*HIDD+u], ao = x[3*HIDD+u];
    for (int k = 0; k < HIDD; ++k) {
        float hv = hl[k];
        const float* wr = Wh + (size_t)k*GATE4;
        ai += hv*wr[u];
        af += hv*wr[HIDD+u];
        ac += hv*wr[2*HIDD+u];
        ao += hv*wr[3*HIDD+u];
    }
    float* cp = cbuf + ((size_t)dir*BATCH + b)*HIDD + u;
    float cold = *cp;
    float si = 1.f/(1.f + expf(-ai));
    float sf = 1.f/(1.f + expf(-af));
    float so = 1.f/(1.f + expf(-ao));
    float cnew = sf*cold + si*tanhf(ac);
    float hnew = so*tanhf(cnew);
    *cp = cnew;
    hbuf[(((size_t)((t+1)&1)*2 + dir)*BATCH + b)*HIDD + u] = hnew;
    if (t < lens[b]) {
        float* ts = tsum + ((size_t)dir*BATCH + b)*HIDD + u;
        *ts += hnew;
    }
}

// kern[which][b] = (tsum[which][b]/128) @ kW + kb ; grid (64,2), block 256, all b fused
__global__ void kern_gemm(const float* __restrict__ tsum,
                          const float* __restrict__ k1W, const float* __restrict__ k1b,
                          const float* __restrict__ k2W, const float* __restrict__ k2b,
                          float* __restrict__ kern)
{
    int which = blockIdx.y;
    int co = blockIdx.x*256 + threadIdx.x;   // < 16384 exact
    __shared__ float te[BATCH][HIDD];        // 9.6 KB
    for (int i = threadIdx.x; i < BATCH*HIDD; i += 256) {
        int b = i / HIDD, k = i % HIDD;
        te[b][k] = tsum[((size_t)which*BATCH + b)*HIDD + k]*(1.f/128.f);
    }
    __syncthreads();
    const float* W    = which ? k2W : k1W;
    const float* bias = which ? k2b : k1b;
    float bv = bias[co];
    float a0=bv, a1=bv, a2=bv, a3=bv;
    for (int k = 0; k < HIDD; ++k) {
        float w = W[(size_t)k*16384 + co];
        a0 += te[0][k]*w; a1 += te[1][k]*w; a2 += te[2][k]*w; a3 += te[3][k]*w;
    }
    kern[((size_t)which*BATCH+0)*16384+co] = a0;
    kern[((size_t)which*BATCH+1)*16384+co] = a1;
    kern[((size_t)which*BATCH+2)*16384+co] = a2;
    kern[((size_t)which*BATCH+3)*16384+co] = a3;
}

// ---- MFMA 5x5 SAME conv via f16 hi/lo split (3-term). 128 ic per pass. ----
// block 256 (4 waves, 2x2 wave grid), tile M=64 px (4 rows x 16 px), N=128 oc.
// MODE 0: store raw; 1: bias+relu; 2: dst+=, bias+relu
template<int MODE>
__global__ __launch_bounds__(256)
void conv5m(const float* __restrict__ src, const _Float16* __restrict__ whi,
            const _Float16* __restrict__ wlo, const float* __restrict__ bias,
            float* __restrict__ dst)
{
    __shared__ _Float16 lds[2*20480];     // hi plane [0,20480), lo plane [20480,40960)
    const int tid = threadIdx.x;
    const int b  = blockIdx.z;
    const int r0 = blockIdx.y*4, p0 = blockIdx.x*16;
    const size_t rowS = (size_t)WW*CC, imgS = (size_t)HH*rowS;
    const float* sb = src + (size_t)b*imgS;

    // stage 8 rows x 20 px x 128 ch, fp32 -> f16 hi/lo, XOR-swizzled on half-index
    for (int it = 0; it < 20; ++it) {
        int idx = it*256 + tid;               // 0..5119
        int c4  = idx & 31;
        int px  = (idx >> 5) % 20;
        int row = idx / 640;
        int gr = r0 + row - 2, gp = p0 + px - 2;
        float4 v = make_float4(0.f,0.f,0.f,0.f);
        if ((unsigned)gr < HH && (unsigned)gp < WW)
            v = *reinterpret_cast<const float4*>(sb + (size_t)gr*rowS + (size_t)gp*CC + c4*4);
        int pix = row*20 + px;
        int ph  = (pix*128 + c4*4) ^ ((pix & 7) << 3);
        _Float16 h0=(_Float16)v.x, h1=(_Float16)v.y, h2=(_Float16)v.z, h3=(_Float16)v.w;
        f16x4 hv = {h0, h1, h2, h3};
        f16x4 lv = {(_Float16)(v.x-(float)h0), (_Float16)(v.y-(float)h1),
                    (_Float16)(v.z-(float)h2), (_Float16)(v.w-(float)h3)};
        *reinterpret_cast<f16x4*>(&lds[ph]) = hv;
        *reinterpret_cast<f16x4*>(&lds[20480 + ph]) = lv;
    }
    __syncthreads();

    const int lane = tid & 63, w = tid >> 6;
    const int wm = w & 1, wn = w >> 1;     // wave grid 2(M) x 2(N)
    const int l15 = lane & 15, kg = lane >> 4;

    f32x4 acc[2][4];
    #pragma unroll
    for (int mi = 0; mi < 2; ++mi)
        #pragma unroll
        for (int ni = 0; ni < 4; ++ni)
            acc[mi][ni] = (f32x4){0.f,0.f,0.f,0.f};

    const int boff = (wn*64 + l15)*128 + kg*8;   // B frag per-lane offset (halfs)

    for (int dy = 0; dy < 5; ++dy) {
        for (int dx = 0; dx < 5; ++dx) {
            const int tap = dy*5 + dx;
            const _Float16* wbh = whi + ((size_t)tap << 14) + boff;
            const _Float16* wbl = wlo + ((size_t)tap << 14) + boff;
            int pix0 = (wm*2 + dy)*20 + l15 + dx;       // mi=0 input pixel
            int a0 = pix0*128 + kg*8;       int sw0 = (pix0 & 7) << 3;
            int pix1 = pix0 + 20;                        // mi=1 (next image row)
            int a1 = pix1*128 + kg*8;       int sw1 = (pix1 & 7) << 3;
            for (int kt = 0; kt < 4; ++kt) {
                f16x8 bh0 = *(const f16x8*)(wbh + kt*32);
                f16x8 bh1 = *(const f16x8*)(wbh + kt*32 + 2048);
                f16x8 bh2 = *(const f16x8*)(wbh + kt*32 + 4096);
                f16x8 bh3 = *(const f16x8*)(wbh + kt*32 + 6144);
                f16x8 bl0 = *(const f16x8*)(wbl + kt*32);
                f16x8 bl1 = *(const f16x8*)(wbl + kt*32 + 2048);
                f16x8 bl2 = *(const f16x8*)(wbl + kt*32 + 4096);
                f16x8 bl3 = *(const f16x8*)(wbl + kt*32 + 6144);
                f16x8 ah0 = *(const f16x8*)&lds[(a0 + kt*32) ^ sw0];
                f16x8 al0 = *(const f16x8*)&lds[20480 + ((a0 + kt*32) ^ sw0)];
                f16x8 ah1 = *(const f16x8*)&lds[(a1 + kt*32) ^ sw1];
                f16x8 al1 = *(const f16x8*)&lds[20480 + ((a1 + kt*32) ^ sw1)];
#define SPLIT_MFMA(mi, ni, AH, AL, BH, BL)                                          \
    acc[mi][ni] = __builtin_amdgcn_mfma_f32_16x16x32_f16(AH, BH, acc[mi][ni],0,0,0);\
    acc[mi][ni] = __builtin_amdgcn_mfma_f32_16x16x32_f16(AH, BL, acc[mi][ni],0,0,0);\
    acc[mi][ni] = __builtin_amdgcn_mfma_f32_16x16x32_f16(AL, BH, acc[mi][ni],0,0,0);
                SPLIT_MFMA(0,0, ah0, al0, bh0, bl0)
                SPLIT_MFMA(0,1, ah0, al0, bh1, bl1)
                SPLIT_MFMA(0,2, ah0, al0, bh2, bl2)
                SPLIT_MFMA(0,3, ah0, al0, bh3, bl3)
                SPLIT_MFMA(1,0, ah1, al1, bh0, bl0)
                SPLIT_MFMA(1,1, ah1, al1, bh1, bl1)
                SPLIT_MFMA(1,2, ah1, al1, bh2, bl2)
                SPLIT_MFMA(1,3, ah1, al1, bh3, bl3)
#undef SPLIT_MFMA
            }
        }
    }

    // epilogue: D col = lane&15 (oc), row = kg*4 + q (pixel along width)
    #pragma unroll
    for (int ni = 0; ni < 4; ++ni) {
        int oc = wn*64 + ni*16 + l15;
        float bv = (MODE != 0) ? bias[oc] : 0.f;
        #pragma unroll
        for (int mi = 0; mi < 2; ++mi) {
            float* op = dst + (size_t)b*imgS + (size_t)(r0 + wm*2 + mi)*rowS
                            + (size_t)(p0 + kg*4)*CC + oc;
            f32x4 a = acc[mi][ni];
            #pragma unroll
            for (int q = 0; q < 4; ++q) {
                float v = a[q];
                float* ap = op + (size_t)q*CC;
                if (MODE == 0)      *ap = v;
                else if (MODE == 1) *ap = fmaxf(v + bv, 0.f);
                else                *ap = fmaxf(v + *ap + bv, 0.f);
            }
        }
    }
}

// g[b,p,o] = sum_c src[b,p,c]*kern[b,c,o]
__global__ void chanmul(const float* __restrict__ src, const float* __restrict__ kern,
                        float* __restrict__ dst)
{
    __shared__ float kl[CC*CC];   // 64 KB
    int b  = blockIdx.y;
    int p0 = blockIdx.x*32;
    const float* kb = kern + (size_t)b*CC*CC;
    for (int i = threadIdx.x; i < CC*CC/4; i += 256)
        reinterpret_cast<float4*>(kl)[i] = reinterpret_cast<const float4*>(kb)[i];
    __syncthreads();
    int ocg = threadIdx.x & 31, pxg = threadIdx.x >> 5;
    int oc0 = ocg*4;
    const float* xs = src + ((size_t)b*NPIX + p0 + pxg*4)*CC;
    float acc[4][4] = {};
    for (int c = 0; c < CC; ++c) {
        float4 wv = *reinterpret_cast<const float4*>(kl + c*CC + oc0);
        #pragma unroll
        for (int pp = 0; pp < 4; ++pp) {
            float xv = xs[(size_t)pp*CC + c];
            acc[pp][0] += xv*wv.x; acc[pp][1] += xv*wv.y;
            acc[pp][2] += xv*wv.z; acc[pp][3] += xv*wv.w;
        }
    }
    #pragma unroll
    for (int pp = 0; pp < 4; ++pp) {
        float* o = dst + ((size_t)b*NPIX + p0 + pxg*4 + pp)*CC + oc0;
        o[0]=acc[pp][0]; o[1]=acc[pp][1]; o[2]=acc[pp][2]; o[3]=acc[pp][3];
    }
}

// per-pixel MLP head: o1=relu(x@d1W+b), o2=relu(o1@d2W+b), logit=o2@oW
__global__ void head(const float* __restrict__ h1,
                     const float* __restrict__ d1W, const float* __restrict__ d1b,
                     const float* __restrict__ d2W, const float* __restrict__ d2b,
                     const float* __restrict__ oW, float* __restrict__ out)
{
    int half = threadIdx.x >> 7;
    int j    = threadIdx.x & 127;
    int px   = blockIdx.x*2 + half;
    __shared__ float xv[2][CC];
    __shared__ float o1[2][CC];
    __shared__ float red[4];
    xv[half][j] = h1[(size_t)px*CC + j];
    __syncthreads();
    float a = d1b[j];
    for (int c = 0; c < CC; ++c) a += xv[half][c]*d1W[c*CC + j];
    a = fmaxf(a, 0.f);
    o1[half][j] = a;
    __syncthreads();
    float a2 = d2b[j];
    for (int c = 0; c < CC; ++c) a2 += o1[half][c]*d2W[c*CC + j];
    a2 = fmaxf(a2, 0.f);
    float contrib = a2*oW[j];
    for (int o = 32; o; o >>= 1) contrib += __shfl_down(contrib, o, 64);
    if ((threadIdx.x & 63) == 0) red[threadIdx.x >> 6] = contrib;
    __syncthreads();
    if (threadIdx.x == 0)   out[px] = red[0] + red[1];
    if (threadIdx.x == 128) out[px] = red[2] + red[3];
}

// in-place softmax over rows of 46400
__global__ void softmax_rows(float* __restrict__ out)
{
    int b = blockIdx.x;
    float* row = out + (size_t)b*NPIX;
    __shared__ float red[16];
    float m = -3.4e38f;
    for (int i = threadIdx.x; i < NPIX; i += 1024) m = fmaxf(m, row[i]);
    for (int o = 32; o; o >>= 1) m = fmaxf(m, __shfl_down(m, o, 64));
    if ((threadIdx.x & 63) == 0) red[threadIdx.x >> 6] = m;
    __syncthreads();
    if (threadIdx.x == 0) {
        float mm = red[0];
        for (int i = 1; i < 16; ++i) mm = fmaxf(mm, red[i]);
        red[0] = mm;
    }
    __syncthreads();
    m = red[0];
    __syncthreads();
    float s = 0.f;
    for (int i = threadIdx.x; i < NPIX; i += 1024) s += expf(row[i] - m);
    for (int o = 32; o; o >>= 1) s += __shfl_down(s, o, 64);
    if ((threadIdx.x & 63) == 0) red[threadIdx.x >> 6] = s;
    __syncthreads();
    if (threadIdx.x == 0) {
        float ss = 0.f;
        for (int i = 0; i < 16; ++i) ss += red[i];
        red[0] = ss;
    }
    __syncthreads();
    float inv = 1.f/red[0];
    for (int i = threadIdx.x; i < NPIX; i += 1024) row[i] = expf(row[i] - m)*inv;
}

extern "C" void kernel_launch(void* const* d_in, const int* in_sizes, int n_in,
                              void* d_out, int out_size, void* d_ws, size_t ws_size,
                              hipStream_t stream) {
    (void)in_sizes; (void)n_in; (void)out_size; (void)ws_size;
    const float* img  = (const float*)d_in[0];
    const int* instr  = (const int*)d_in[1];
    const int* lens   = (const int*)d_in[2];
    const float* etab = (const float*)d_in[3];
    const float* fWx  = (const float*)d_in[4];
    const float* fWh  = (const float*)d_in[5];
    const float* fb   = (const float*)d_in[6];
    const float* bWx  = (const float*)d_in[7];
    const float* bWh  = (const float*)d_in[8];
    const float* bb   = (const float*)d_in[9];
    const float* k1W  = (const float*)d_in[10];
    const float* k1b  = (const float*)d_in[11];
    const float* k2W  = (const float*)d_in[12];
    const float* k2b  = (const float*)d_in[13];
    const float* c1w  = (const float*)d_in[14];
    const float* c1b  = (const float*)d_in[15];
    const float* c2w  = (const float*)d_in[16];
    const float* c2b  = (const float*)d_in[17];
    const float* dc1w = (const float*)d_in[18];
    const float* dc1b = (const float*)d_in[19];
    const float* dc2w = (const float*)d_in[20];
    const float* dc2b = (const float*)d_in[21];
    const float* d1W  = (const float*)d_in[22];
    const float* d1b  = (const float*)d_in[23];
    const float* d2W  = (const float*)d_in[24];
    const float* d2b  = (const float*)d_in[25];
    const float* oW   = (const float*)d_in[26];
    float* out = (float*)d_out;
    float* ws  = (float*)d_ws;

    float* A  = ws + OFF_A;
    float* Bb = ws + OFF_B;
    float* Cb = ws + OFF_C;
    float* xg = ws + OFF_XG;
    float* hb = ws + OFF_H;
    float* cb = ws + OFF_CS;
    float* ts = ws + OFF_TS;
    float* kn = ws + OFF_K;
    _Float16* whi = (_Float16*)(ws + OFF_W);
    _Float16* wlo = whi + WELEMS;

    // weight pre-conversion (f16 hi/lo transposed planes)
    wcvt<<<WELEMS/256, 256, 0, stream>>>(c1w, c2w, dc2w, dc1w, whi, wlo);
    // zero LSTM state + text sums (contiguous region)
    zero_f<<<dim3((int)((SZ_H+SZ_CS+SZ_TS+255)/256)), 256, 0, stream>>>(hb, (int)(SZ_H+SZ_CS+SZ_TS));
    // embedding + input-gate precompute for both directions (tiled over t)
    embed_xg<<<dim3(10, 64), 256, 0, stream>>>(instr, lens, etab, fWx, fb, bWx, bb, xg);
    // recurrence
    for (int t = 0; t < TSEQ; ++t)
        lstm_step<<<24, 256, 0, stream>>>(xg, fWh, bWh, lens, hb, cb, ts, t);
    // text kernels (all b fused)
    kern_gemm<<<dim3(64, 2), 256, 0, stream>>>(ts, k1W, k1b, k2W, k2b, kn);
    // conv stack (MFMA f16-split)
    dim3 cgrid(WW/16, HH/4, BATCH);   // (29, 25, 4)
    conv5m<1><<<cgrid, 256, 0, stream>>>(img, whi + 0*WSLOT, wlo + 0*WSLOT, c1b, A);    // f1 -> A
    conv5m<1><<<cgrid, 256, 0, stream>>>(A,   whi + 1*WSLOT, wlo + 1*WSLOT, c2b, Bb);   // f2 -> B
    chanmul<<<dim3(NPIX/32, BATCH), 256, 0, stream>>>(A,  kn, Cb);                       // g1 -> C
    chanmul<<<dim3(NPIX/32, BATCH), 256, 0, stream>>>(Bb, kn + (size_t)BATCH*CC*CC, A);  // g2 -> A
    conv5m<1><<<cgrid, 256, 0, stream>>>(A,  whi + 2*WSLOT, wlo + 2*WSLOT, dc2b, Bb);   // h2 -> B
    conv5m<0><<<cgrid, 256, 0, stream>>>(Bb, whi + 3*WSLOT, wlo + 3*WSLOT, dc1b, A);    // h1 partial (h2 part)
    conv5m<2><<<cgrid, 256, 0, stream>>>(Cb, whi + 4*WSLOT, wlo + 4*WSLOT, dc1b, A);    // h1 += g1 part, bias+relu
    // head + softmax
    head<<<dim3(BATCH*NPIX/2), 256, 0, stream>>>(A, d1W, d1b, d2W, d2b, oW, out);
    softmax_rows<<<dim3(BATCH), 1024, 0, stream>>>(out);
}

// Round 4
// 5287.391 us; speedup vs baseline: 9.5580x; 9.5580x over previous
//
#include <hip/hip_runtime.h>
#include <cmath>

#define BATCH 4
#define TSEQ  128
#define HH    100
#define WW    464
#define CC    128
#define EMBD  300
#define HIDD  600
#define GATE4 2400
#define NPIX  (HH*WW)                 // 46400
#define IMG   ((size_t)BATCH*NPIX*CC) // 23,756,800 floats

// ---- workspace layout (in floats) ----
#define OFF_A  ((size_t)0)
#define OFF_B  (IMG)
#define OFF_C  (2*IMG)                // WhT (11.5MB) overlaid here until chanmul
#define OFF_XG (3*IMG)
#define SZ_XG  ((size_t)2*BATCH*TSEQ*GATE4)   // 2,457,600
#define OFF_H  (OFF_XG + SZ_XG)
#define SZ_H   ((size_t)2*2*BATCH*HIDD)        // 9600 (parity,dir,b,u)
#define OFF_CS (OFF_H + SZ_H)
#define SZ_CS  ((size_t)2*BATCH*HIDD)          // 4800
#define OFF_TS (OFF_CS + SZ_CS)
#define SZ_TS  ((size_t)2*BATCH*HIDD)          // 4800
#define OFF_K  (OFF_TS + SZ_TS)
#define SZ_K   ((size_t)2*BATCH*CC*CC)         // 131072
#define OFF_W  (OFF_K + SZ_K)
#define WSLOT  (25*CC*CC)                      // 409,600 halfs per slot
#define WELEMS (5*WSLOT)                       // 2,048,000 halfs per plane

typedef _Float16 f16x8 __attribute__((ext_vector_type(8)));
typedef _Float16 f16x4 __attribute__((ext_vector_type(4)));
typedef float    f32x4 __attribute__((ext_vector_type(4)));

__global__ void zero_f(float* p, int n) {
    int i = blockIdx.x*blockDim.x + threadIdx.x;
    if (i < n) p[i] = 0.f;
}

// ---- weight pre-convert: fp32 (tap,ic,oc) -> f16 hi/lo FRAGMENT-ORDER planes ----
// per slot, per tap (16384 halfs): [wn(2)][kt(4)][ni(4)][lane(64)][e(8)]
//   lane = kg*16 + l15 ;  oc = wn*64 + ni*16 + l15 ;  ic = kt*32 + kg*8 + e
// slots: 0=conv1 1=conv2 2=deconv2 3=deconv1[ic 0..127 = h2] 4=deconv1[ic 128..255 = g1]
__global__ void wcvt(const float* __restrict__ c1, const float* __restrict__ c2,
                     const float* __restrict__ dc2, const float* __restrict__ dc1,
                     _Float16* __restrict__ whi, _Float16* __restrict__ wlo)
{
    int e0 = blockIdx.x*256 + threadIdx.x;      // < WELEMS
    int slot = e0 / WSLOT;
    int r = e0 % WSLOT;
    int tap = r >> 14;
    int idx = r & 16383;
    int e    = idx & 7;
    int lane = (idx >> 3) & 63;
    int ni   = (idx >> 9) & 3;
    int kt   = (idx >> 11) & 3;
    int wn   = (idx >> 13) & 1;
    int l15 = lane & 15, kg = lane >> 4;
    int oc = wn*64 + ni*16 + l15;
    int ic = kt*32 + kg*8 + e;
    const float* s; size_t si;
    if      (slot == 0) { s = c1;  si = ((size_t)tap*128 + ic)*128 + oc; }
    else if (slot == 1) { s = c2;  si = ((size_t)tap*128 + ic)*128 + oc; }
    else if (slot == 2) { s = dc2; si = ((size_t)tap*128 + ic)*128 + oc; }
    else if (slot == 3) { s = dc1; si = ((size_t)tap*256 + ic)*128 + oc; }
    else                { s = dc1; si = ((size_t)tap*256 + 128 + ic)*128 + oc; }
    float v = s[si];
    _Float16 h  = (_Float16)v;
    _Float16 lo = (_Float16)(v - (float)h);
    whi[e0] = h; wlo[e0] = lo;
}

// ---- Wh transpose: whT[dir][j(2400)][k(600)] = Wh_dir[k][j] ; grid (10,2), block 256
__global__ void wh_t(const float* __restrict__ fWh, const float* __restrict__ bWh,
                     float* __restrict__ whT)
{
    int j = blockIdx.x*256 + threadIdx.x;
    int dir = blockIdx.y;
    if (j >= GATE4) return;
    const float* W = dir ? bWh : fWh;
    float* o = whT + ((size_t)dir*GATE4 + j)*HIDD;
    for (int k = 0; k < HIDD; k += 4) {
        float4 v;
        v.x = W[(size_t)k*GATE4 + j];
        v.y = W[(size_t)(k+1)*GATE4 + j];
        v.z = W[(size_t)(k+2)*GATE4 + j];
        v.w = W[(size_t)(k+3)*GATE4 + j];
        *reinterpret_cast<float4*>(o + k) = v;
    }
}

// text = embed[instr]; xg[dir] = (dir? rev(text):text) @ Wx + b
// tiled: 16 timesteps per block. grid (10, 64), block 256
__global__ void embed_xg(const int* __restrict__ instr, const int* __restrict__ lens,
                         const float* __restrict__ etab,
                         const float* __restrict__ fWx, const float* __restrict__ fb,
                         const float* __restrict__ bWx, const float* __restrict__ bb,
                         float* __restrict__ xg)
{
    int gy  = blockIdx.y;
    int dir = gy >> 5;
    int b   = (gy >> 3) & 3;
    int tt  = gy & 7;
    int t0  = tt*16;
    int j   = blockIdx.x*256 + threadIdx.x;
    __shared__ int tok[16];
    __shared__ __attribute__((aligned(16))) float rows_t[EMBD][16];  // 19.2 KB
    int L = lens[b];
    if (threadIdx.x < 16) {
        int t = t0 + threadIdx.x;
        int tsel = (dir == 1 && t < L) ? (L - 1 - t) : t;
        tok[threadIdx.x] = instr[b*TSEQ + tsel];
    }
    __syncthreads();
    for (int idx = threadIdx.x; idx < 16*EMBD; idx += 256) {
        int k = idx >> 4, r = idx & 15;
        rows_t[k][r] = etab[(size_t)tok[r]*EMBD + k];
    }
    __syncthreads();
    if (j >= GATE4) return;
    const float* Wx   = dir ? bWx : fWx;
    const float* bias = dir ? bb  : fb;
    float bv = bias[j];
    float acc[16];
    #pragma unroll
    for (int r = 0; r < 16; ++r) acc[r] = bv;
    for (int k = 0; k < EMBD; ++k) {
        float w = Wx[(size_t)k*GATE4 + j];
        float4 a0 = *reinterpret_cast<const float4*>(&rows_t[k][0]);
        float4 a1 = *reinterpret_cast<const float4*>(&rows_t[k][4]);
        float4 a2 = *reinterpret_cast<const float4*>(&rows_t[k][8]);
        float4 a3 = *reinterpret_cast<const float4*>(&rows_t[k][12]);
        acc[0]+=a0.x*w;  acc[1]+=a0.y*w;  acc[2]+=a0.z*w;  acc[3]+=a0.w*w;
        acc[4]+=a1.x*w;  acc[5]+=a1.y*w;  acc[6]+=a1.z*w;  acc[7]+=a1.w*w;
        acc[8]+=a2.x*w;  acc[9]+=a2.y*w;  acc[10]+=a2.z*w; acc[11]+=a2.w*w;
        acc[12]+=a3.x*w; acc[13]+=a3.y*w; acc[14]+=a3.z*w; acc[15]+=a3.w*w;
    }
    float* o = xg + ((size_t)(dir*BATCH + b)*TSEQ + t0)*GATE4 + j;
    #pragma unroll
    for (int r = 0; r < 16; ++r) o[(size_t)r*GATE4] = acc[r];
}

// ---- LSTM step v2: one warp per (dir,u), lanes split k, all 4 b batched. ----
// grid 300 (dir = blk/150, u = (blk%150)*4 + wid), block 256 (4 warps)
__global__ __launch_bounds__(256)
void lstm_step2(const float* __restrict__ xg, const float* __restrict__ whT,
                const int* __restrict__ lens,
                float* __restrict__ hbuf, float* __restrict__ cbuf,
                float* __restrict__ tsum, int t)
{
    int blk = blockIdx.x;
    int dir = blk / 150;
    int u   = (blk % 150)*4 + (threadIdx.x >> 6);
    int lane = threadIdx.x & 63;
    __shared__ float hl[BATCH][HIDD];    // 9.6 KB
    const float* hprev = hbuf + (((size_t)(t&1)*2 + dir)*BATCH)*HIDD;
    for (int i = threadIdx.x; i < BATCH*HIDD; i += 256) hl[i/HIDD][i % HIDD] = hprev[i];
    __syncthreads();
    const float* wr = whT + (size_t)dir*GATE4*HIDD;
    float acc[4][4] = {};   // [gate][b] — all static-indexed
    #pragma unroll
    for (int i = 0; i < 10; ++i) {
        int k = i*64 + lane;
        if (k < HIDD) {
            float h0 = hl[0][k], h1 = hl[1][k], h2 = hl[2][k], h3 = hl[3][k];
            #pragma unroll
            for (int g = 0; g < 4; ++g) {
                float w = wr[(size_t)(g*HIDD + u)*HIDD + k];
                acc[g][0] += w*h0; acc[g][1] += w*h1;
                acc[g][2] += w*h2; acc[g][3] += w*h3;
            }
        }
    }
    #pragma unroll
    for (int off = 32; off; off >>= 1) {
        #pragma unroll
        for (int g = 0; g < 4; ++g) {
            acc[g][0] += __shfl_xor(acc[g][0], off, 64);
            acc[g][1] += __shfl_xor(acc[g][1], off, 64);
            acc[g][2] += __shfl_xor(acc[g][2], off, 64);
            acc[g][3] += __shfl_xor(acc[g][3], off, 64);
        }
    }
    if (lane == 0) {
        #pragma unroll
        for (int b = 0; b < 4; ++b) {
            const float* x = xg + ((size_t)(dir*BATCH + b)*TSEQ + t)*GATE4;
            float ai = x[u]          + acc[0][b];
            float af = x[HIDD + u]   + acc[1][b];
            float ac = x[2*HIDD + u] + acc[2][b];
            float ao = x[3*HIDD + u] + acc[3][b];
            size_t ci = ((size_t)dir*BATCH + b)*HIDD + u;
            float cold = cbuf[ci];
            float si = 1.f/(1.f + expf(-ai));
            float sf = 1.f/(1.f + expf(-af));
            float so = 1.f/(1.f + expf(-ao));
            float cnew = sf*cold + si*tanhf(ac);
            float hnew = so*tanhf(cnew);
            cbuf[ci] = cnew;
            hbuf[(((size_t)((t+1)&1)*2 + dir)*BATCH + b)*HIDD + u] = hnew;
            if (t < lens[b]) tsum[ci] += hnew;
        }
    }
}

// kern[which][b] = (tsum[which][b]/128) @ kW + kb ; grid (64,2), block 256, all b fused
__global__ void kern_gemm(const float* __restrict__ tsum,
                          const float* __restrict__ k1W, const float* __restrict__ k1b,
                          const float* __restrict__ k2W, const float* __restrict__ k2b,
                          float* __restrict__ kern)
{
    int which = blockIdx.y;
    int co = blockIdx.x*256 + threadIdx.x;   // < 16384 exact
    __shared__ float te[BATCH][HIDD];        // 9.6 KB
    for (int i = threadIdx.x; i < BATCH*HIDD; i += 256) {
        int b = i / HIDD, k = i % HIDD;
        te[b][k] = tsum[((size_t)which*BATCH + b)*HIDD + k]*(1.f/128.f);
    }
    __syncthreads();
    const float* W    = which ? k2W : k1W;
    const float* bias = which ? k2b : k1b;
    float bv = bias[co];
    float a0=bv, a1=bv, a2=bv, a3=bv;
    for (int k = 0; k < HIDD; ++k) {
        float w = W[(size_t)k*16384 + co];
        a0 += te[0][k]*w; a1 += te[1][k]*w; a2 += te[2][k]*w; a3 += te[3][k]*w;
    }
    kern[((size_t)which*BATCH+0)*16384+co] = a0;
    kern[((size_t)which*BATCH+1)*16384+co] = a1;
    kern[((size_t)which*BATCH+2)*16384+co] = a2;
    kern[((size_t)which*BATCH+3)*16384+co] = a3;
}

// ---- MFMA 5x5 SAME conv via f16 hi/lo split (3-term). 128 ic per pass. ----
// block 256 (4 waves, 2x2 wave grid), tile M=64 px (4 rows x 16 px), N=128 oc.
// weights in fragment order: per tap [wn][kt][ni][lane][8] -> 1KB coalesced wave loads
// MODE 0: store raw; 1: bias+relu; 2: dst+=, bias+relu
template<int MODE>
__global__ __launch_bounds__(256)
void conv5m(const float* __restrict__ src, const _Float16* __restrict__ whi,
            const _Float16* __restrict__ wlo, const float* __restrict__ bias,
            float* __restrict__ dst)
{
    __shared__ _Float16 lds[2*20480];     // hi plane [0,20480), lo plane [20480,40960)
    const int tid = threadIdx.x;
    const int b  = blockIdx.z;
    const int r0 = blockIdx.y*4, p0 = blockIdx.x*16;
    const size_t rowS = (size_t)WW*CC, imgS = (size_t)HH*rowS;
    const float* sb = src + (size_t)b*imgS;

    // stage 8 rows x 20 px x 128 ch, fp32 -> f16 hi/lo, XOR-swizzled on half-index
    for (int it = 0; it < 20; ++it) {
        int idx = it*256 + tid;               // 0..5119
        int c4  = idx & 31;
        int px  = (idx >> 5) % 20;
        int row = idx / 640;
        int gr = r0 + row - 2, gp = p0 + px - 2;
        float4 v = make_float4(0.f,0.f,0.f,0.f);
        if ((unsigned)gr < HH && (unsigned)gp < WW)
            v = *reinterpret_cast<const float4*>(sb + (size_t)gr*rowS + (size_t)gp*CC + c4*4);
        int pix = row*20 + px;
        int ph  = (pix*128 + c4*4) ^ ((pix & 7) << 3);
        _Float16 h0=(_Float16)v.x, h1=(_Float16)v.y, h2=(_Float16)v.z, h3=(_Float16)v.w;
        f16x4 hv = {h0, h1, h2, h3};
        f16x4 lv = {(_Float16)(v.x-(float)h0), (_Float16)(v.y-(float)h1),
                    (_Float16)(v.z-(float)h2), (_Float16)(v.w-(float)h3)};
        *reinterpret_cast<f16x4*>(&lds[ph]) = hv;
        *reinterpret_cast<f16x4*>(&lds[20480 + ph]) = lv;
    }
    __syncthreads();

    const int lane = tid & 63, w = tid >> 6;
    const int wm = w & 1, wn = w >> 1;     // wave grid 2(M) x 2(N)
    const int l15 = lane & 15, kg = lane >> 4;

    f32x4 acc[2][4];
    #pragma unroll
    for (int mi = 0; mi < 2; ++mi)
        #pragma unroll
        for (int ni = 0; ni < 4; ++ni)
            acc[mi][ni] = (f32x4){0.f,0.f,0.f,0.f};

    for (int dy = 0; dy < 5; ++dy) {
        for (int dx = 0; dx < 5; ++dx) {
            const int tap = dy*5 + dx;
            const _Float16* wth = whi + ((size_t)tap << 14) + wn*8192 + lane*8;
            const _Float16* wtl = wlo + ((size_t)tap << 14) + wn*8192 + lane*8;
            int pix0 = (wm*2 + dy)*20 + l15 + dx;        // mi=0 input pixel
            int a0 = pix0*128 + kg*8;       int sw0 = (pix0 & 7) << 3;
            int pix1 = pix0 + 20;                         // mi=1 (next image row)
            int a1 = pix1*128 + kg*8;       int sw1 = (pix1 & 7) << 3;
            for (int kt = 0; kt < 4; ++kt) {
                const _Float16* ph = wth + kt*2048;
                const _Float16* pl = wtl + kt*2048;
                f16x8 bh0 = *(const f16x8*)(ph);
                f16x8 bh1 = *(const f16x8*)(ph + 512);
                f16x8 bh2 = *(const f16x8*)(ph + 1024);
                f16x8 bh3 = *(const f16x8*)(ph + 1536);
                f16x8 bl0 = *(const f16x8*)(pl);
                f16x8 bl1 = *(const f16x8*)(pl + 512);
                f16x8 bl2 = *(const f16x8*)(pl + 1024);
                f16x8 bl3 = *(const f16x8*)(pl + 1536);
                f16x8 ah0 = *(const f16x8*)&lds[(a0 + kt*32) ^ sw0];
                f16x8 al0 = *(const f16x8*)&lds[20480 + ((a0 + kt*32) ^ sw0)];
                f16x8 ah1 = *(const f16x8*)&lds[(a1 + kt*32) ^ sw1];
                f16x8 al1 = *(const f16x8*)&lds[20480 + ((a1 + kt*32) ^ sw1)];
#define SPLIT_MFMA(mi, ni, AH, AL, BH, BL)                                          \
    acc[mi][ni] = __builtin_amdgcn_mfma_f32_16x16x32_f16(AH, BH, acc[mi][ni],0,0,0);\
    acc[mi][ni] = __builtin_amdgcn_mfma_f32_16x16x32_f16(AH, BL, acc[mi][ni],0,0,0);\
    acc[mi][ni] = __builtin_amdgcn_mfma_f32_16x16x32_f16(AL, BH, acc[mi][ni],0,0,0);
                SPLIT_MFMA(0,0, ah0, al0, bh0, bl0)
                SPLIT_MFMA(0,1, ah0, al0, bh1, bl1)
                SPLIT_MFMA(0,2, ah0, al0, bh2, bl2)
                SPLIT_MFMA(0,3, ah0, al0, bh3, bl3)
                SPLIT_MFMA(1,0, ah1, al1, bh0, bl0)
                SPLIT_MFMA(1,1, ah1, al1, bh1, bl1)
                SPLIT_MFMA(1,2, ah1, al1, bh2, bl2)
                SPLIT_MFMA(1,3, ah1, al1, bh3, bl3)
#undef SPLIT_MFMA
            }
        }
    }

    // epilogue: D col = lane&15 (oc), row = kg*4 + q (pixel along width)
    #pragma unroll
    for (int ni = 0; ni < 4; ++ni) {
        int oc = wn*64 + ni*16 + l15;
        float bv = (MODE != 0) ? bias[oc] : 0.f;
        #pragma unroll
        for (int mi = 0; mi < 2; ++mi) {
            float* op = dst + (size_t)b*imgS + (size_t)(r0 + wm*2 + mi)*rowS
                            + (size_t)(p0 + kg*4)*CC + oc;
            f32x4 a = acc[mi][ni];
            #pragma unroll
            for (int q = 0; q < 4; ++q) {
                float v = a[q];
                float* ap = op + (size_t)q*CC;
                if (MODE == 0)      *ap = v;
                else if (MODE == 1) *ap = fmaxf(v + bv, 0.f);
                else                *ap = fmaxf(v + *ap + bv, 0.f);
            }
        }
    }
}

// g[b,p,o] = sum_c src[b,p,c]*kern[b,c,o]
__global__ void chanmul(const float* __restrict__ src, const float* __restrict__ kern,
                        float* __restrict__ dst)
{
    __shared__ float kl[CC*CC];   // 64 KB
    int b  = blockIdx.y;
    int p0 = blockIdx.x*32;
    const float* kb = kern + (size_t)b*CC*CC;
    for (int i = threadIdx.x; i < CC*CC/4; i += 256)
        reinterpret_cast<float4*>(kl)[i] = reinterpret_cast<const float4*>(kb)[i];
    __syncthreads();
    int ocg = threadIdx.x & 31, pxg = threadIdx.x >> 5;
    int oc0 = ocg*4;
    const float* xs = src + ((size_t)b*NPIX + p0 + pxg*4)*CC;
    float acc[4][4] = {};
    for (int c = 0; c < CC; ++c) {
        float4 wv = *reinterpret_cast<const float4*>(kl + c*CC + oc0);
        #pragma unroll
        for (int pp = 0; pp < 4; ++pp) {
            float xv = xs[(size_t)pp*CC + c];
            acc[pp][0] += xv*wv.x; acc[pp][1] += xv*wv.y;
            acc[pp][2] += xv*wv.z; acc[pp][3] += xv*wv.w;
        }
    }
    #pragma unroll
    for (int pp = 0; pp < 4; ++pp) {
        float* o = dst + ((size_t)b*NPIX + p0 + pxg*4 + pp)*CC + oc0;
        o[0]=acc[pp][0]; o[1]=acc[pp][1]; o[2]=acc[pp][2]; o[3]=acc[pp][3];
    }
}

// per-pixel MLP head: o1=relu(x@d1W+b), o2=relu(o1@d2W+b), logit=o2@oW
__global__ void head(const float* __restrict__ h1,
                     const float* __restrict__ d1W, const float* __restrict__ d1b,
                     const float* __restrict__ d2W, const float* __restrict__ d2b,
                     const float* __restrict__ oW, float* __restrict__ out)
{
    int half = threadIdx.x >> 7;
    int j    = threadIdx.x & 127;
    int px   = blockIdx.x*2 + half;
    __shared__ float xv[2][CC];
    __shared__ float o1[2][CC];
    __shared__ float red[4];
    xv[half][j] = h1[(size_t)px*CC + j];
    __syncthreads();
    float a = d1b[j];
    for (int c = 0; c < CC; ++c) a += xv[half][c]*d1W[c*CC + j];
    a = fmaxf(a, 0.f);
    o1[half][j] = a;
    __syncthreads();
    float a2 = d2b[j];
    for (int c = 0; c < CC; ++c) a2 += o1[half][c]*d2W[c*CC + j];
    a2 = fmaxf(a2, 0.f);
    float contrib = a2*oW[j];
    for (int o = 32; o; o >>= 1) contrib += __shfl_down(contrib, o, 64);
    if ((threadIdx.x & 63) == 0) red[threadIdx.x >> 6] = contrib;
    __syncthreads();
    if (threadIdx.x == 0)   out[px] = red[0] + red[1];
    if (threadIdx.x == 128) out[px] = red[2] + red[3];
}

// in-place softmax over rows of 46400
__global__ void softmax_rows(float* __restrict__ out)
{
    int b = blockIdx.x;
    float* row = out + (size_t)b*NPIX;
    __shared__ float red[16];
    float m = -3.4e38f;
    for (int i = threadIdx.x; i < NPIX; i += 1024) m = fmaxf(m, row[i]);
    for (int o = 32; o; o >>= 1) m = fmaxf(m, __shfl_down(m, o, 64));
    if ((threadIdx.x & 63) == 0) red[threadIdx.x >> 6] = m;
    __syncthreads();
    if (threadIdx.x == 0) {
        float mm = red[0];
        for (int i = 1; i < 16; ++i) mm = fmaxf(mm, red[i]);
        red[0] = mm;
    }
    __syncthreads();
    m = red[0];
    __syncthreads();
    float s = 0.f;
    for (int i = threadIdx.x; i < NPIX; i += 1024) s += expf(row[i] - m);
    for (int o = 32; o; o >>= 1) s += __shfl_down(s, o, 64);
    if ((threadIdx.x & 63) == 0) red[threadIdx.x >> 6] = s;
    __syncthreads();
    if (threadIdx.x == 0) {
        float ss = 0.f;
        for (int i = 0; i < 16; ++i) ss += red[i];
        red[0] = ss;
    }
    __syncthreads();
    float inv = 1.f/red[0];
    for (int i = threadIdx.x; i < NPIX; i += 1024) row[i] = expf(row[i] - m)*inv;
}

extern "C" void kernel_launch(void* const* d_in, const int* in_sizes, int n_in,
                              void* d_out, int out_size, void* d_ws, size_t ws_size,
                              hipStream_t stream) {
    (void)in_sizes; (void)n_in; (void)out_size; (void)ws_size;
    const float* img  = (const float*)d_in[0];
    const int* instr  = (const int*)d_in[1];
    const int* lens   = (const int*)d_in[2];
    const float* etab = (const float*)d_in[3];
    const float* fWx  = (const float*)d_in[4];
    const float* fWh  = (const float*)d_in[5];
    const float* fb   = (const float*)d_in[6];
    const float* bWx  = (const float*)d_in[7];
    const float* bWh  = (const float*)d_in[8];
    const float* bb   = (const float*)d_in[9];
    const float* k1W  = (const float*)d_in[10];
    const float* k1b  = (const float*)d_in[11];
    const float* k2W  = (const float*)d_in[12];
    const float* k2b  = (const float*)d_in[13];
    const float* c1w  = (const float*)d_in[14];
    const float* c1b  = (const float*)d_in[15];
    const float* c2w  = (const float*)d_in[16];
    const float* c2b  = (const float*)d_in[17];
    const float* dc1w = (const float*)d_in[18];
    const float* dc1b = (const float*)d_in[19];
    const float* dc2w = (const float*)d_in[20];
    const float* dc2b = (const float*)d_in[21];
    const float* d1W  = (const float*)d_in[22];
    const float* d1b  = (const float*)d_in[23];
    const float* d2W  = (const float*)d_in[24];
    const float* d2b  = (const float*)d_in[25];
    const float* oW   = (const float*)d_in[26];
    float* out = (float*)d_out;
    float* ws  = (float*)d_ws;

    float* A  = ws + OFF_A;
    float* Bb = ws + OFF_B;
    float* Cb = ws + OFF_C;
    float* xg = ws + OFF_XG;
    float* hb = ws + OFF_H;
    float* cb = ws + OFF_CS;
    float* ts = ws + OFF_TS;
    float* kn = ws + OFF_K;
    _Float16* whi = (_Float16*)(ws + OFF_W);
    _Float16* wlo = whi + WELEMS;
    float* whT = Cb;   // overlay: dead until chanmul writes g1

    // weight pre-conversion (f16 hi/lo fragment-order planes) + Wh transpose
    wcvt<<<WELEMS/256, 256, 0, stream>>>(c1w, c2w, dc2w, dc1w, whi, wlo);
    wh_t<<<dim3(10, 2), 256, 0, stream>>>(fWh, bWh, whT);
    // zero LSTM state + text sums (contiguous region)
    zero_f<<<dim3((int)((SZ_H+SZ_CS+SZ_TS+255)/256)), 256, 0, stream>>>(hb, (int)(SZ_H+SZ_CS+SZ_TS));
    // embedding + input-gate precompute for both directions (tiled over t)
    embed_xg<<<dim3(10, 64), 256, 0, stream>>>(instr, lens, etab, fWx, fb, bWx, bb, xg);
    // recurrence (warp-per-u, k split across lanes)
    for (int t = 0; t < TSEQ; ++t)
        lstm_step2<<<300, 256, 0, stream>>>(xg, whT, lens, hb, cb, ts, t);
    // text kernels (all b fused)
    kern_gemm<<<dim3(64, 2), 256, 0, stream>>>(ts, k1W, k1b, k2W, k2b, kn);
    // conv stack (MFMA f16-split)
    dim3 cgrid(WW/16, HH/4, BATCH);   // (29, 25, 4)
    conv5m<1><<<cgrid, 256, 0, stream>>>(img, whi + 0*WSLOT, wlo + 0*WSLOT, c1b, A);    // f1 -> A
    conv5m<1><<<cgrid, 256, 0, stream>>>(A,   whi + 1*WSLOT, wlo + 1*WSLOT, c2b, Bb);   // f2 -> B
    chanmul<<<dim3(NPIX/32, BATCH), 256, 0, stream>>>(A,  kn, Cb);                       // g1 -> C (kills WhT)
    chanmul<<<dim3(NPIX/32, BATCH), 256, 0, stream>>>(Bb, kn + (size_t)BATCH*CC*CC, A);  // g2 -> A
    conv5m<1><<<cgrid, 256, 0, stream>>>(A,  whi + 2*WSLOT, wlo + 2*WSLOT, dc2b, Bb);   // h2 -> B
    conv5m<0><<<cgrid, 256, 0, stream>>>(Bb, whi + 3*WSLOT, wlo + 3*WSLOT, dc1b, A);    // h1 partial (h2 part)
    conv5m<2><<<cgrid, 256, 0, stream>>>(Cb, whi + 4*WSLOT, wlo + 4*WSLOT, dc1b, A);    // h1 += g1 part, bias+relu
    // head + softmax
    head<<<dim3(BATCH*NPIX/2), 256, 0, stream>>>(A, d1W, d1b, d2W, d2b, oW, out);
    softmax_rows<<<dim3(BATCH), 1024, 0, stream>>>(out);
}

// Round 6
// 4704.298 us; speedup vs baseline: 10.7427x; 1.1239x over previous
//
#include <hip/hip_runtime.h>
#include <cmath>

#define BATCH 4
#define TSEQ  128
#define HH    100
#define WW    464
#define CC    128
#define EMBD  300
#define HIDD  600
#define GATE4 2400
#define NPIX  (HH*WW)                 // 46400
#define IMG   ((size_t)BATCH*NPIX*CC) // 23,756,800 floats

// ---- workspace layout (in floats) ----
#define OFF_A  ((size_t)0)
#define OFF_B  (IMG)
#define OFF_C  (2*IMG)                // WhT (11.5MB) overlaid here until chanmul
#define OFF_XG (3*IMG)
#define SZ_XG  ((size_t)2*BATCH*TSEQ*GATE4)   // 2,457,600
#define OFF_H  (OFF_XG + SZ_XG)
#define SZ_H   ((size_t)2*2*BATCH*HIDD)        // 9600 (parity,dir,b,u)
#define OFF_CS (OFF_H + SZ_H)
#define SZ_CS  ((size_t)2*BATCH*HIDD)          // 4800
#define OFF_TS (OFF_CS + SZ_CS)
#define SZ_TS  ((size_t)2*BATCH*HIDD)          // 4800
#define OFF_K  (OFF_TS + SZ_TS)
#define SZ_K   ((size_t)2*BATCH*CC*CC)         // 131072
#define OFF_W  (OFF_TS + SZ_TS + SZ_K)
#define WSLOT  (25*CC*CC)                      // 409,600 halfs per slot
#define WELEMS (5*WSLOT)                       // 2,048,000 halfs per plane
#define OFF_WH (OFF_W + WELEMS)                // head weights: 65536 halfs (32768 floats)

typedef _Float16 f16x8 __attribute__((ext_vector_type(8)));
typedef _Float16 f16x4 __attribute__((ext_vector_type(4)));
typedef float    f32x4 __attribute__((ext_vector_type(4)));

__global__ void zero_f(float* p, int n) {
    int i = blockIdx.x*blockDim.x + threadIdx.x;
    if (i < n) p[i] = 0.f;
}

__device__ __forceinline__ void cvt8(float4 v0, float4 v1, f16x8& h, f16x8& l) {
    _Float16 h0=(_Float16)v0.x, h1=(_Float16)v0.y, h2=(_Float16)v0.z, h3=(_Float16)v0.w;
    _Float16 h4=(_Float16)v1.x, h5=(_Float16)v1.y, h6=(_Float16)v1.z, h7=(_Float16)v1.w;
    h = (f16x8){h0,h1,h2,h3,h4,h5,h6,h7};
    l = (f16x8){(_Float16)(v0.x-(float)h0), (_Float16)(v0.y-(float)h1),
                (_Float16)(v0.z-(float)h2), (_Float16)(v0.w-(float)h3),
                (_Float16)(v1.x-(float)h4), (_Float16)(v1.y-(float)h5),
                (_Float16)(v1.z-(float)h6), (_Float16)(v1.w-(float)h7)};
}

// ---- weight pre-convert: fp32 (tap,ic,oc) -> f16 hi/lo FRAGMENT-ORDER planes ----
// per slot, per tap (16384 halfs): [wn(2)][kt(4)][ni(4)][lane(64)][e(8)]
//   lane = kg*16 + l15 ;  oc = wn*64 + ni*16 + l15 ;  ic = kt*32 + kg*8 + e
// slots: 0=conv1 1=conv2 2=deconv2 3=deconv1[ic 0..127 = h2] 4=deconv1[ic 128..255 = g1]
__global__ void wcvt(const float* __restrict__ c1, const float* __restrict__ c2,
                     const float* __restrict__ dc2, const float* __restrict__ dc1,
                     _Float16* __restrict__ whi, _Float16* __restrict__ wlo)
{
    int e0 = blockIdx.x*256 + threadIdx.x;      // < WELEMS
    int slot = e0 / WSLOT;
    int r = e0 % WSLOT;
    int tap = r >> 14;
    int idx = r & 16383;
    int e    = idx & 7;
    int lane = (idx >> 3) & 63;
    int ni   = (idx >> 9) & 3;
    int kt   = (idx >> 11) & 3;
    int wn   = (idx >> 13) & 1;
    int l15 = lane & 15, kg = lane >> 4;
    int oc = wn*64 + ni*16 + l15;
    int ic = kt*32 + kg*8 + e;
    const float* s; size_t si;
    if      (slot == 0) { s = c1;  si = ((size_t)tap*128 + ic)*128 + oc; }
    else if (slot == 1) { s = c2;  si = ((size_t)tap*128 + ic)*128 + oc; }
    else if (slot == 2) { s = dc2; si = ((size_t)tap*128 + ic)*128 + oc; }
    else if (slot == 3) { s = dc1; si = ((size_t)tap*256 + ic)*128 + oc; }
    else                { s = dc1; si = ((size_t)tap*256 + 128 + ic)*128 + oc; }
    float v = s[si];
    _Float16 h  = (_Float16)v;
    _Float16 lo = (_Float16)(v - (float)h);
    whi[e0] = h; wlo[e0] = lo;
}

// ---- head weights: d1W,d2W (128x128, [k][oc]) -> frag order [which][hi/lo][kt][ni(8)][lane][8]
__global__ void wcvt_head(const float* __restrict__ d1W, const float* __restrict__ d2W,
                          _Float16* __restrict__ whd)
{
    int e0 = blockIdx.x*256 + threadIdx.x;      // < 32768
    int which = e0 >> 14;
    int idx = e0 & 16383;
    int e    = idx & 7;
    int lane = (idx >> 3) & 63;
    int ni   = (idx >> 9) & 7;
    int kt   = (idx >> 12) & 3;
    int l15 = lane & 15, kg = lane >> 4;
    int oc = ni*16 + l15;
    int k  = kt*32 + kg*8 + e;
    const float* W = which ? d2W : d1W;
    float v = W[(size_t)k*CC + oc];
    _Float16 h  = (_Float16)v;
    _Float16 lo = (_Float16)(v - (float)h);
    whd[(size_t)which*32768 + idx]         = h;
    whd[(size_t)which*32768 + 16384 + idx] = lo;
}

// ---- Wh transpose: whT[dir][j(2400)][k(600)] = Wh_dir[k][j] ; grid (10,2), block 256
__global__ void wh_t(const float* __restrict__ fWh, const float* __restrict__ bWh,
                     float* __restrict__ whT)
{
    int j = blockIdx.x*256 + threadIdx.x;
    int dir = blockIdx.y;
    if (j >= GATE4) return;
    const float* W = dir ? bWh : fWh;
    float* o = whT + ((size_t)dir*GATE4 + j)*HIDD;
    for (int k = 0; k < HIDD; k += 4) {
        float4 v;
        v.x = W[(size_t)k*GATE4 + j];
        v.y = W[(size_t)(k+1)*GATE4 + j];
        v.z = W[(size_t)(k+2)*GATE4 + j];
        v.w = W[(size_t)(k+3)*GATE4 + j];
        *reinterpret_cast<float4*>(o + k) = v;
    }
}

// text = embed[instr]; xg[dir] = (dir? rev(text):text) @ Wx + b
// tiled: 16 timesteps per block. grid (10, 64), block 256
__global__ void embed_xg(const int* __restrict__ instr, const int* __restrict__ lens,
                         const float* __restrict__ etab,
                         const float* __restrict__ fWx, const float* __restrict__ fb,
                         const float* __restrict__ bWx, const float* __restrict__ bb,
                         float* __restrict__ xg)
{
    int gy  = blockIdx.y;
    int dir = gy >> 5;
    int b   = (gy >> 3) & 3;
    int tt  = gy & 7;
    int t0  = tt*16;
    int j   = blockIdx.x*256 + threadIdx.x;
    __shared__ int tok[16];
    __shared__ __attribute__((aligned(16))) float rows_t[EMBD][16];  // 19.2 KB
    int L = lens[b];
    if (threadIdx.x < 16) {
        int t = t0 + threadIdx.x;
        int tsel = (dir == 1 && t < L) ? (L - 1 - t) : t;
        tok[threadIdx.x] = instr[b*TSEQ + tsel];
    }
    __syncthreads();
    for (int idx = threadIdx.x; idx < 16*EMBD; idx += 256) {
        int k = idx >> 4, r = idx & 15;
        rows_t[k][r] = etab[(size_t)tok[r]*EMBD + k];
    }
    __syncthreads();
    if (j >= GATE4) return;
    const float* Wx   = dir ? bWx : fWx;
    const float* bias = dir ? bb  : fb;
    float bv = bias[j];
    float acc[16];
    #pragma unroll
    for (int r = 0; r < 16; ++r) acc[r] = bv;
    for (int k = 0; k < EMBD; ++k) {
        float w = Wx[(size_t)k*GATE4 + j];
        float4 a0 = *reinterpret_cast<const float4*>(&rows_t[k][0]);
        float4 a1 = *reinterpret_cast<const float4*>(&rows_t[k][4]);
        float4 a2 = *reinterpret_cast<const float4*>(&rows_t[k][8]);
        float4 a3 = *reinterpret_cast<const float4*>(&rows_t[k][12]);
        acc[0]+=a0.x*w;  acc[1]+=a0.y*w;  acc[2]+=a0.z*w;  acc[3]+=a0.w*w;
        acc[4]+=a1.x*w;  acc[5]+=a1.y*w;  acc[6]+=a1.z*w;  acc[7]+=a1.w*w;
        acc[8]+=a2.x*w;  acc[9]+=a2.y*w;  acc[10]+=a2.z*w; acc[11]+=a2.w*w;
        acc[12]+=a3.x*w; acc[13]+=a3.y*w; acc[14]+=a3.z*w; acc[15]+=a3.w*w;
    }
    float* o = xg + ((size_t)(dir*BATCH + b)*TSEQ + t0)*GATE4 + j;
    #pragma unroll
    for (int r = 0; r < 16; ++r) o[(size_t)r*GATE4] = acc[r];
}

// ---- LSTM step v2: one warp per (dir,u), lanes split k, all 4 b batched. ----
__global__ __launch_bounds__(256)
void lstm_step2(const float* __restrict__ xg, const float* __restrict__ whT,
                const int* __restrict__ lens,
                float* __restrict__ hbuf, float* __restrict__ cbuf,
                float* __restrict__ tsum, int t)
{
    int blk = blockIdx.x;
    int dir = blk / 150;
    int u   = (blk % 150)*4 + (threadIdx.x >> 6);
    int lane = threadIdx.x & 63;
    __shared__ float hl[BATCH][HIDD];    // 9.6 KB
    const float* hprev = hbuf + (((size_t)(t&1)*2 + dir)*BATCH)*HIDD;
    for (int i = threadIdx.x; i < BATCH*HIDD; i += 256) hl[i/HIDD][i % HIDD] = hprev[i];
    __syncthreads();
    const float* wr = whT + (size_t)dir*GATE4*HIDD;
    float acc[4][4] = {};   // [gate][b] — all static-indexed
    #pragma unroll
    for (int i = 0; i < 10; ++i) {
        int k = i*64 + lane;
        if (k < HIDD) {
            float h0 = hl[0][k], h1 = hl[1][k], h2 = hl[2][k], h3 = hl[3][k];
            #pragma unroll
            for (int g = 0; g < 4; ++g) {
                float w = wr[(size_t)(g*HIDD + u)*HIDD + k];
                acc[g][0] += w*h0; acc[g][1] += w*h1;
                acc[g][2] += w*h2; acc[g][3] += w*h3;
            }
        }
    }
    #pragma unroll
    for (int off = 32; off; off >>= 1) {
        #pragma unroll
        for (int g = 0; g < 4; ++g) {
            acc[g][0] += __shfl_xor(acc[g][0], off, 64);
            acc[g][1] += __shfl_xor(acc[g][1], off, 64);
            acc[g][2] += __shfl_xor(acc[g][2], off, 64);
            acc[g][3] += __shfl_xor(acc[g][3], off, 64);
        }
    }
    if (lane == 0) {
        #pragma unroll
        for (int b = 0; b < 4; ++b) {
            const float* x = xg + ((size_t)(dir*BATCH + b)*TSEQ + t)*GATE4;
            float ai = x[u]          + acc[0][b];
            float af = x[HIDD + u]   + acc[1][b];
            float ac = x[2*HIDD + u] + acc[2][b];
            float ao = x[3*HIDD + u] + acc[3][b];
            size_t ci = ((size_t)dir*BATCH + b)*HIDD + u;
            float cold = cbuf[ci];
            float si = 1.f/(1.f + expf(-ai));
            float sf = 1.f/(1.f + expf(-af));
            float so = 1.f/(1.f + expf(-ao));
            float cnew = sf*cold + si*tanhf(ac);
            float hnew = so*tanhf(cnew);
            cbuf[ci] = cnew;
            hbuf[(((size_t)((t+1)&1)*2 + dir)*BATCH + b)*HIDD + u] = hnew;
            if (t < lens[b]) tsum[ci] += hnew;
        }
    }
}

// kern[which][b] = (tsum[which][b]/128) @ kW + kb ; grid (64,2), block 256, all b fused
__global__ void kern_gemm(const float* __restrict__ tsum,
                          const float* __restrict__ k1W, const float* __restrict__ k1b,
                          const float* __restrict__ k2W, const float* __restrict__ k2b,
                          float* __restrict__ kern)
{
    int which = blockIdx.y;
    int co = blockIdx.x*256 + threadIdx.x;   // < 16384 exact
    __shared__ float te[BATCH][HIDD];        // 9.6 KB
    for (int i = threadIdx.x; i < BATCH*HIDD; i += 256) {
        int b = i / HIDD, k = i % HIDD;
        te[b][k] = tsum[((size_t)which*BATCH + b)*HIDD + k]*(1.f/128.f);
    }
    __syncthreads();
    const float* W    = which ? k2W : k1W;
    const float* bias = which ? k2b : k1b;
    float bv = bias[co];
    float a0=bv, a1=bv, a2=bv, a3=bv;
    for (int k = 0; k < HIDD; ++k) {
        float w = W[(size_t)k*16384 + co];
        a0 += te[0][k]*w; a1 += te[1][k]*w; a2 += te[2][k]*w; a3 += te[3][k]*w;
    }
    kern[((size_t)which*BATCH+0)*16384+co] = a0;
    kern[((size_t)which*BATCH+1)*16384+co] = a1;
    kern[((size_t)which*BATCH+2)*16384+co] = a2;
    kern[((size_t)which*BATCH+3)*16384+co] = a3;
}

// ---- MFMA 5x5 SAME conv via f16 hi/lo split (3-term). 128 ic per pass. ----
// block 256 (4 waves, 2x2 wave grid), tile M=64 px (4 rows x 16 px), N=128 oc.
// weights in fragment order: per tap [wn][kt][ni][lane][8] -> 1KB coalesced wave loads
// MODE 0: store raw; 1: bias+relu; 2: dst+=, bias+relu
template<int MODE>
__global__ __launch_bounds__(256)
void conv5m(const float* __restrict__ src, const _Float16* __restrict__ whi,
            const _Float16* __restrict__ wlo, const float* __restrict__ bias,
            float* __restrict__ dst)
{
    __shared__ _Float16 lds[2*20480];     // hi plane [0,20480), lo plane [20480,40960)
    const int tid = threadIdx.x;
    const int b  = blockIdx.z;
    const int r0 = blockIdx.y*4, p0 = blockIdx.x*16;
    const size_t rowS = (size_t)WW*CC, imgS = (size_t)HH*rowS;
    const float* sb = src + (size_t)b*imgS;

    // stage 8 rows x 20 px x 128 ch, fp32 -> f16 hi/lo, XOR-swizzled on half-index
    for (int it = 0; it < 20; ++it) {
        int idx = it*256 + tid;               // 0..5119
        int c4  = idx & 31;
        int px  = (idx >> 5) % 20;
        int row = idx / 640;
        int gr = r0 + row - 2, gp = p0 + px - 2;
        float4 v = make_float4(0.f,0.f,0.f,0.f);
        if ((unsigned)gr < HH && (unsigned)gp < WW)
            v = *reinterpret_cast<const float4*>(sb + (size_t)gr*rowS + (size_t)gp*CC + c4*4);
        int pix = row*20 + px;
        int ph  = (pix*128 + c4*4) ^ ((pix & 7) << 3);
        _Float16 h0=(_Float16)v.x, h1=(_Float16)v.y, h2=(_Float16)v.z, h3=(_Float16)v.w;
        f16x4 hv = {h0, h1, h2, h3};
        f16x4 lv = {(_Float16)(v.x-(float)h0), (_Float16)(v.y-(float)h1),
                    (_Float16)(v.z-(float)h2), (_Float16)(v.w-(float)h3)};
        *reinterpret_cast<f16x4*>(&lds[ph]) = hv;
        *reinterpret_cast<f16x4*>(&lds[20480 + ph]) = lv;
    }
    __syncthreads();

    const int lane = tid & 63, w = tid >> 6;
    const int wm = w & 1, wn = w >> 1;     // wave grid 2(M) x 2(N)
    const int l15 = lane & 15, kg = lane >> 4;

    f32x4 acc[2][4];
    #pragma unroll
    for (int mi = 0; mi < 2; ++mi)
        #pragma unroll
        for (int ni = 0; ni < 4; ++ni)
            acc[mi][ni] = (f32x4){0.f,0.f,0.f,0.f};

    for (int dy = 0; dy < 5; ++dy) {
        for (int dx = 0; dx < 5; ++dx) {
            const int tap = dy*5 + dx;
            const _Float16* wth = whi + ((size_t)tap << 14) + wn*8192 + lane*8;
            const _Float16* wtl = wlo + ((size_t)tap << 14) + wn*8192 + lane*8;
            int pix0 = (wm*2 + dy)*20 + l15 + dx;        // mi=0 input pixel
            int a0 = pix0*128 + kg*8;       int sw0 = (pix0 & 7) << 3;
            int pix1 = pix0 + 20;                         // mi=1 (next image row)
            int a1 = pix1*128 + kg*8;       int sw1 = (pix1 & 7) << 3;
            for (int kt = 0; kt < 4; ++kt) {
                const _Float16* ph = wth + kt*2048;
                const _Float16* pl = wtl + kt*2048;
                f16x8 bh0 = *(const f16x8*)(ph);
                f16x8 bh1 = *(const f16x8*)(ph + 512);
                f16x8 bh2 = *(const f16x8*)(ph + 1024);
                f16x8 bh3 = *(const f16x8*)(ph + 1536);
                f16x8 bl0 = *(const f16x8*)(pl);
                f16x8 bl1 = *(const f16x8*)(pl + 512);
                f16x8 bl2 = *(const f16x8*)(pl + 1024);
                f16x8 bl3 = *(const f16x8*)(pl + 1536);
                f16x8 ah0 = *(const f16x8*)&lds[(a0 + kt*32) ^ sw0];
                f16x8 al0 = *(const f16x8*)&lds[20480 + ((a0 + kt*32) ^ sw0)];
                f16x8 ah1 = *(const f16x8*)&lds[(a1 + kt*32) ^ sw1];
                f16x8 al1 = *(const f16x8*)&lds[20480 + ((a1 + kt*32) ^ sw1)];
#define SPLIT_MFMA(mi, ni, AH, AL, BH, BL)                                          \
    acc[mi][ni] = __builtin_amdgcn_mfma_f32_16x16x32_f16(AH, BH, acc[mi][ni],0,0,0);\
    acc[mi][ni] = __builtin_amdgcn_mfma_f32_16x16x32_f16(AH, BL, acc[mi][ni],0,0,0);\
    acc[mi][ni] = __builtin_amdgcn_mfma_f32_16x16x32_f16(AL, BH, acc[mi][ni],0,0,0);
                SPLIT_MFMA(0,0, ah0, al0, bh0, bl0)
                SPLIT_MFMA(0,1, ah0, al0, bh1, bl1)
                SPLIT_MFMA(0,2, ah0, al0, bh2, bl2)
                SPLIT_MFMA(0,3, ah0, al0, bh3, bl3)
                SPLIT_MFMA(1,0, ah1, al1, bh0, bl0)
                SPLIT_MFMA(1,1, ah1, al1, bh1, bl1)
                SPLIT_MFMA(1,2, ah1, al1, bh2, bl2)
                SPLIT_MFMA(1,3, ah1, al1, bh3, bl3)
#undef SPLIT_MFMA
            }
        }
    }

    // epilogue: D col = lane&15 (oc), row = kg*4 + q (pixel along width)
    #pragma unroll
    for (int ni = 0; ni < 4; ++ni) {
        int oc = wn*64 + ni*16 + l15;
        float bv = (MODE != 0) ? bias[oc] : 0.f;
        #pragma unroll
        for (int mi = 0; mi < 2; ++mi) {
            float* op = dst + (size_t)b*imgS + (size_t)(r0 + wm*2 + mi)*rowS
                            + (size_t)(p0 + kg*4)*CC + oc;
            f32x4 a = acc[mi][ni];
            #pragma unroll
            for (int q = 0; q < 4; ++q) {
                float v = a[q];
                float* ap = op + (size_t)q*CC;
                if (MODE == 0)      *ap = v;
                else if (MODE == 1) *ap = fmaxf(v + bv, 0.f);
                else                *ap = fmaxf(v + *ap + bv, 0.f);
            }
        }
    }
}

// g[b,p,o] = sum_c src[b,p,c]*kern[b,c,o]
__global__ void chanmul(const float* __restrict__ src, const float* __restrict__ kern,
                        float* __restrict__ dst)
{
    __shared__ float kl[CC*CC];   // 64 KB
    int b  = blockIdx.y;
    int p0 = blockIdx.x*32;
    const float* kb = kern + (size_t)b*CC*CC;
    for (int i = threadIdx.x; i < CC*CC/4; i += 256)
        reinterpret_cast<float4*>(kl)[i] = reinterpret_cast<const float4*>(kb)[i];
    __syncthreads();
    int ocg = threadIdx.x & 31, pxg = threadIdx.x >> 5;
    int oc0 = ocg*4;
    const float* xs = src + ((size_t)b*NPIX + p0 + pxg*4)*CC;
    float acc[4][4] = {};
    for (int c = 0; c < CC; ++c) {
        float4 wv = *reinterpret_cast<const float4*>(kl + c*CC + oc0);
        #pragma unroll
        for (int pp = 0; pp < 4; ++pp) {
            float xv = xs[(size_t)pp*CC + c];
            acc[pp][0] += xv*wv.x; acc[pp][1] += xv*wv.y;
            acc[pp][2] += xv*wv.z; acc[pp][3] += xv*wv.w;
        }
    }
    #pragma unroll
    for (int pp = 0; pp < 4; ++pp) {
        float* o = dst + ((size_t)b*NPIX + p0 + pxg*4 + pp)*CC + oc0;
        o[0]=acc[pp][0]; o[1]=acc[pp][1]; o[2]=acc[pp][2]; o[3]=acc[pp][3];
    }
}

// ---- MFMA head: per block 128 px, 4 waves x 32 px; o1=relu(X@W1+b1); o2=relu(o1@W2+b2);
// logit = o2 . oW.  grid 1450, block 256
__global__ __launch_bounds__(256)
void head_mfma(const float* __restrict__ X, const _Float16* __restrict__ whd,
               const float* __restrict__ d1b, const float* __restrict__ d2b,
               const float* __restrict__ oW, float* __restrict__ out)
{
    __shared__ float o1s[4][4096];   // 64 KB: per-wave 32px x 128oc (swizzled)
    const int tid = threadIdx.x;
    const int lane = tid & 63, w = tid >> 6;
    const int l15 = lane & 15, kg = lane >> 4;
    const size_t pxbase = (size_t)blockIdx.x*128 + w*32;
    float* o1w = o1s[w];

    const _Float16* w1 = whd;            // [kt][ni][lane][8] hi ; +16384 lo
    const _Float16* w2 = whd + 32768;

    // ---- GEMM1: o1 = relu(X @ W1 + b1) ----
    f32x4 acc[2][8];
    #pragma unroll
    for (int ni = 0; ni < 8; ++ni) {
        float bv = d1b[ni*16 + l15];
        acc[0][ni] = (f32x4){bv,bv,bv,bv};
        acc[1][ni] = (f32x4){bv,bv,bv,bv};
    }
    #pragma unroll
    for (int kt = 0; kt < 4; ++kt) {
        f16x8 ah0, al0, ah1, al1;
        {
            const float* xp = X + (pxbase + l15)*CC + kt*32 + kg*8;
            cvt8(*(const float4*)xp, *(const float4*)(xp+4), ah0, al0);
            const float* xq = xp + 16*CC;
            cvt8(*(const float4*)xq, *(const float4*)(xq+4), ah1, al1);
        }
        #pragma unroll
        for (int ni = 0; ni < 8; ++ni) {
            const _Float16* bp = w1 + (((size_t)kt*8 + ni)*64 + lane)*8;
            f16x8 bh = *(const f16x8*)bp;
            f16x8 bl = *(const f16x8*)(bp + 16384);
            acc[0][ni] = __builtin_amdgcn_mfma_f32_16x16x32_f16(ah0, bh, acc[0][ni],0,0,0);
            acc[0][ni] = __builtin_amdgcn_mfma_f32_16x16x32_f16(ah0, bl, acc[0][ni],0,0,0);
            acc[0][ni] = __builtin_amdgcn_mfma_f32_16x16x32_f16(al0, bh, acc[0][ni],0,0,0);
            acc[1][ni] = __builtin_amdgcn_mfma_f32_16x16x32_f16(ah1, bh, acc[1][ni],0,0,0);
            acc[1][ni] = __builtin_amdgcn_mfma_f32_16x16x32_f16(ah1, bl, acc[1][ni],0,0,0);
            acc[1][ni] = __builtin_amdgcn_mfma_f32_16x16x32_f16(al1, bh, acc[1][ni],0,0,0);
        }
    }
    // relu -> LDS (float-index swizzle ^((px&7)<<3)); wave-private region, no barrier needed
    #pragma unroll
    for (int mi = 0; mi < 2; ++mi)
        #pragma unroll
        for (int ni = 0; ni < 8; ++ni) {
            f32x4 a = acc[mi][ni];
            #pragma unroll
            for (int q = 0; q < 4; ++q) {
                int px = mi*16 + kg*4 + q;
                int oc = ni*16 + l15;
                o1w[(px*128 + oc) ^ ((px & 7) << 3)] = fmaxf(a[q], 0.f);
            }
        }

    // ---- GEMM2: o2 = relu(o1 @ W2 + b2) ----
    f32x4 acc2[2][8];
    #pragma unroll
    for (int ni = 0; ni < 8; ++ni) {
        float bv = d2b[ni*16 + l15];
        acc2[0][ni] = (f32x4){bv,bv,bv,bv};
        acc2[1][ni] = (f32x4){bv,bv,bv,bv};
    }
    #pragma unroll
    for (int kt = 0; kt < 4; ++kt) {
        f16x8 ah0, al0, ah1, al1;
        {
            int px0 = l15;
            int i0 = (px0*128 + kt*32 + kg*8) ^ ((px0 & 7) << 3);
            cvt8(*(const float4*)&o1w[i0], *(const float4*)&o1w[i0+4], ah0, al0);
            int px1 = 16 + l15;
            int i1 = (px1*128 + kt*32 + kg*8) ^ ((px1 & 7) << 3);
            cvt8(*(const float4*)&o1w[i1], *(const float4*)&o1w[i1+4], ah1, al1);
        }
        #pragma unroll
        for (int ni = 0; ni < 8; ++ni) {
            const _Float16* bp = w2 + (((size_t)kt*8 + ni)*64 + lane)*8;
            f16x8 bh = *(const f16x8*)bp;
            f16x8 bl = *(const f16x8*)(bp + 16384);
            acc2[0][ni] = __builtin_amdgcn_mfma_f32_16x16x32_f16(ah0, bh, acc2[0][ni],0,0,0);
            acc2[0][ni] = __builtin_amdgcn_mfma_f32_16x16x32_f16(ah0, bl, acc2[0][ni],0,0,0);
            acc2[0][ni] = __builtin_amdgcn_mfma_f32_16x16x32_f16(al0, bh, acc2[0][ni],0,0,0);
            acc2[1][ni] = __builtin_amdgcn_mfma_f32_16x16x32_f16(ah1, bh, acc2[1][ni],0,0,0);
            acc2[1][ni] = __builtin_amdgcn_mfma_f32_16x16x32_f16(ah1, bl, acc2[1][ni],0,0,0);
            acc2[1][ni] = __builtin_amdgcn_mfma_f32_16x16x32_f16(al1, bh, acc2[1][ni],0,0,0);
        }
    }

    // ---- logit = relu(o2) . oW ; reduce over oc (l15 groups of 16 lanes) ----
    #pragma unroll
    for (int mi = 0; mi < 2; ++mi) {
        float p0 = 0.f, p1 = 0.f, p2 = 0.f, p3 = 0.f;
        #pragma unroll
        for (int ni = 0; ni < 8; ++ni) {
            float ow = oW[ni*16 + l15];
            f32x4 a = acc2[mi][ni];
            p0 += fmaxf(a[0], 0.f)*ow;
            p1 += fmaxf(a[1], 0.f)*ow;
            p2 += fmaxf(a[2], 0.f)*ow;
            p3 += fmaxf(a[3], 0.f)*ow;
        }
        #pragma unroll
        for (int off = 1; off < 16; off <<= 1) {
            p0 += __shfl_xor(p0, off, 64);
            p1 += __shfl_xor(p1, off, 64);
            p2 += __shfl_xor(p2, off, 64);
            p3 += __shfl_xor(p3, off, 64);
        }
        if (l15 == 0) {
            float* op = out + pxbase + mi*16 + kg*4;
            op[0] = p0; op[1] = p1; op[2] = p2; op[3] = p3;
        }
    }
}

// in-place softmax over rows of 46400
__global__ void softmax_rows(float* __restrict__ out)
{
    int b = blockIdx.x;
    float* row = out + (size_t)b*NPIX;
    __shared__ float red[16];
    float m = -3.4e38f;
    for (int i = threadIdx.x; i < NPIX; i += 1024) m = fmaxf(m, row[i]);
    for (int o = 32; o; o >>= 1) m = fmaxf(m, __shfl_down(m, o, 64));
    if ((threadIdx.x & 63) == 0) red[threadIdx.x >> 6] = m;
    __syncthreads();
    if (threadIdx.x == 0) {
        float mm = red[0];
        for (int i = 1; i < 16; ++i) mm = fmaxf(mm, red[i]);
        red[0] = mm;
    }
    __syncthreads();
    m = red[0];
    __syncthreads();
    float s = 0.f;
    for (int i = threadIdx.x; i < NPIX; i += 1024) s += expf(row[i] - m);
    for (int o = 32; o; o >>= 1) s += __shfl_down(s, o, 64);
    if ((threadIdx.x & 63) == 0) red[threadIdx.x >> 6] = s;
    __syncthreads();
    if (threadIdx.x == 0) {
        float ss = 0.f;
        for (int i = 0; i < 16; ++i) ss += red[i];
        red[0] = ss;
    }
    __syncthreads();
    float inv = 1.f/red[0];
    for (int i = threadIdx.x; i < NPIX; i += 1024) row[i] = expf(row[i] - m)*inv;
}

extern "C" void kernel_launch(void* const* d_in, const int* in_sizes, int n_in,
                              void* d_out, int out_size, void* d_ws, size_t ws_size,
                              hipStream_t stream) {
    (void)in_sizes; (void)n_in; (void)out_size; (void)ws_size;
    const float* img  = (const float*)d_in[0];
    const int* instr  = (const int*)d_in[1];
    const int* lens   = (const int*)d_in[2];
    const float* etab = (const float*)d_in[3];
    const float* fWx  = (const float*)d_in[4];
    const float* fWh  = (const float*)d_in[5];
    const float* fb   = (const float*)d_in[6];
    const float* bWx  = (const float*)d_in[7];
    const float* bWh  = (const float*)d_in[8];
    const float* bb   = (const float*)d_in[9];
    const float* k1W  = (const float*)d_in[10];
    const float* k1b  = (const float*)d_in[11];
    const float* k2W  = (const float*)d_in[12];
    const float* k2b  = (const float*)d_in[13];
    const float* c1w  = (const float*)d_in[14];
    const float* c1b  = (const float*)d_in[15];
    const float* c2w  = (const float*)d_in[16];
    const float* c2b  = (const float*)d_in[17];
    const float* dc1w = (const float*)d_in[18];
    const float* dc1b = (const float*)d_in[19];
    const float* dc2w = (const float*)d_in[20];
    const float* dc2b = (const float*)d_in[21];
    const float* d1W  = (const float*)d_in[22];
    const float* d1b  = (const float*)d_in[23];
    const float* d2W  = (const float*)d_in[24];
    const float* d2b  = (const float*)d_in[25];
    const float* oW   = (const float*)d_in[26];
    float* out = (float*)d_out;
    float* ws  = (float*)d_ws;

    float* A  = ws + OFF_A;
    float* Bb = ws + OFF_B;
    float* Cb = ws + OFF_C;
    float* xg = ws + OFF_XG;
    float* hb = ws + OFF_H;
    float* cb = ws + OFF_CS;
    float* ts = ws + OFF_TS;
    float* kn = ws + OFF_K;
    _Float16* whi = (_Float16*)(ws + OFF_W);
    _Float16* wlo = whi + WELEMS;
    _Float16* whd = (_Float16*)(ws + OFF_WH);
    float* whT = Cb;   // overlay: dead until chanmul writes g1

    // weight pre-conversion (f16 hi/lo fragment-order planes) + Wh transpose
    wcvt<<<WELEMS/256, 256, 0, stream>>>(c1w, c2w, dc2w, dc1w, whi, wlo);
    wcvt_head<<<128, 256, 0, stream>>>(d1W, d2W, whd);
    wh_t<<<dim3(10, 2), 256, 0, stream>>>(fWh, bWh, whT);
    // zero LSTM state + text sums (contiguous region)
    zero_f<<<dim3((int)((SZ_H+SZ_CS+SZ_TS+255)/256)), 256, 0, stream>>>(hb, (int)(SZ_H+SZ_CS+SZ_TS));
    // embedding + input-gate precompute for both directions (tiled over t)
    embed_xg<<<dim3(10, 64), 256, 0, stream>>>(instr, lens, etab, fWx, fb, bWx, bb, xg);
    // recurrence (warp-per-u, k split across lanes)
    for (int t = 0; t < TSEQ; ++t)
        lstm_step2<<<300, 256, 0, stream>>>(xg, whT, lens, hb, cb, ts, t);
    // text kernels (all b fused)
    kern_gemm<<<dim3(64, 2), 256, 0, stream>>>(ts, k1W, k1b, k2W, k2b, kn);
    // conv stack (MFMA f16-split)
    dim3 cgrid(WW/16, HH/4, BATCH);   // (29, 25, 4)
    conv5m<1><<<cgrid, 256, 0, stream>>>(img, whi + 0*WSLOT, wlo + 0*WSLOT, c1b, A);    // f1 -> A
    conv5m<1><<<cgrid, 256, 0, stream>>>(A,   whi + 1*WSLOT, wlo + 1*WSLOT, c2b, Bb);   // f2 -> B
    chanmul<<<dim3(NPIX/32, BATCH), 256, 0, stream>>>(A,  kn, Cb);                       // g1 -> C (kills WhT)
    chanmul<<<dim3(NPIX/32, BATCH), 256, 0, stream>>>(Bb, kn + (size_t)BATCH*CC*CC, A);  // g2 -> A
    conv5m<1><<<cgrid, 256, 0, stream>>>(A,  whi + 2*WSLOT, wlo + 2*WSLOT, dc2b, Bb);   // h2 -> B
    conv5m<0><<<cgrid, 256, 0, stream>>>(Bb, whi + 3*WSLOT, wlo + 3*WSLOT, dc1b, A);    // h1 partial (h2 part)
    conv5m<2><<<cgrid, 256, 0, stream>>>(Cb, whi + 4*WSLOT, wlo + 4*WSLOT, dc1b, A);    // h1 += g1 part, bias+relu
    // head (MFMA) + softmax
    head_mfma<<<1450, 256, 0, stream>>>(A, whd, d1b, d2b, oW, out);
    softmax_rows<<<dim3(BATCH), 1024, 0, stream>>>(out);
}